// Round 6
// baseline (247.513 us; speedup 1.0000x reference)
//
#include <hip/hip_runtime.h>

#define DIM 512
#define H 256
#define W 256

// ---------------------------------------------------------------------------
// Kernel 1: scatter point indices onto the cell->index map (map pre-memset -1)
// ---------------------------------------------------------------------------
__global__ void scatter_map_kernel(const int* __restrict__ pos,
                                   int* __restrict__ map, int n) {
    int i = blockIdx.x * blockDim.x + threadIdx.x;
    if (i < n) {
        int h = pos[2 * i], w = pos[2 * i + 1];
        map[h * W + w] = i;
    }
}

// ---------------------------------------------------------------------------
// Kernel 2: fold the three depthwise kernels into one 7x7 effective kernel.
// Conv runs on the (W,H)-transposed grid, so offset (dh,dw) uses tap
// w[c, dw+pad, dh+pad]  (spatial dims swapped).
// weff layout: [49][DIM]  (offset-major, channel-contiguous -> coalesced)
// ---------------------------------------------------------------------------
__global__ void build_weights_kernel(const float* __restrict__ k3,
                                     const float* __restrict__ b1,
                                     const float* __restrict__ k5,
                                     const float* __restrict__ b2,
                                     const float* __restrict__ k7,
                                     const float* __restrict__ b3,
                                     float* __restrict__ weff,
                                     float* __restrict__ bsum) {
    int o = blockIdx.x;    // 0..48
    int c = threadIdx.x;   // 0..511
    int dh = o / 7 - 3, dw = o % 7 - 3;
    float v = k7[c * 49 + (dw + 3) * 7 + (dh + 3)];
    if (dh >= -2 && dh <= 2 && dw >= -2 && dw <= 2)
        v += k5[c * 25 + (dw + 2) * 5 + (dh + 2)];
    if (dh >= -1 && dh <= 1 && dw >= -1 && dw <= 1)
        v += k3[c * 9 + (dw + 1) * 3 + (dh + 1)];
    weff[o * DIM + c] = v;
    if (o == 0) bsum[c] = b1[c] + b2[c] + b3[c];
}

// ---------------------------------------------------------------------------
// Kernel 3: per-point gather-conv. One block per point, 128 threads x float4.
// First 49 lanes probe the 7x7 neighborhood and compact valid (j,offset)
// pairs into LDS; main loop is wave-uniform over the compacted list.
// out[i,c] = x[i,c] + bsum[c] + sum_valid Weff[o,c] * x[j,c]
// ---------------------------------------------------------------------------
__global__ __launch_bounds__(128) void gather_conv_kernel(
    const float* __restrict__ x, const int* __restrict__ pos,
    const int* __restrict__ map, const float* __restrict__ weff,
    const float* __restrict__ bsum, float* __restrict__ out) {
    int i = blockIdx.x;
    int tid = threadIdx.x;

    __shared__ int s_list[49];
    __shared__ int s_cnt;
    if (tid == 0) s_cnt = 0;
    __syncthreads();

    int h = pos[2 * i], w = pos[2 * i + 1];
    if (tid < 49) {
        int dh = tid / 7 - 3, dw = tid % 7 - 3;
        int hh = h + dh, ww = w + dw;
        if (hh >= 0 && hh < H && ww >= 0 && ww < W) {
            int j = map[hh * W + ww];
            if (j >= 0) {
                int slot = atomicAdd(&s_cnt, 1);
                s_list[slot] = (j << 6) | tid;   // pack: j (15 bits) | offset
            }
        }
    }
    __syncthreads();

    int c = tid * 4;
    float4 acc = *(const float4*)(x + (size_t)i * DIM + c);   // identity (dense add)
    float4 bb  = *(const float4*)(bsum + c);
    acc.x += bb.x; acc.y += bb.y; acc.z += bb.z; acc.w += bb.w;

    int cnt = s_cnt;
    for (int k = 0; k < cnt; ++k) {
        int pk = s_list[k];
        int j = pk >> 6, o = pk & 63;
        float4 wv = *(const float4*)(weff + o * DIM + c);
        float4 xv = *(const float4*)(x + (size_t)j * DIM + c);
        acc.x = fmaf(wv.x, xv.x, acc.x);
        acc.y = fmaf(wv.y, xv.y, acc.y);
        acc.z = fmaf(wv.z, xv.z, acc.z);
        acc.w = fmaf(wv.w, xv.w, acc.w);
    }
    *(float4*)(out + (size_t)i * DIM + c) = acc;
}

extern "C" void kernel_launch(void* const* d_in, const int* in_sizes, int n_in,
                              void* d_out, int out_size, void* d_ws, size_t ws_size,
                              hipStream_t stream) {
    const float* x   = (const float*)d_in[0];
    const int*   pos = (const int*)d_in[1];
    const float* k3  = (const float*)d_in[2];
    const float* b1  = (const float*)d_in[3];
    const float* k5  = (const float*)d_in[4];
    const float* b2  = (const float*)d_in[5];
    const float* k7  = (const float*)d_in[6];
    const float* b3  = (const float*)d_in[7];
    float* out = (float*)d_out;

    char* ws = (char*)d_ws;
    int*   map  = (int*)ws;                                   // H*W*4   = 256 KB
    float* weff = (float*)(ws + (size_t)H * W * 4);           // 49*512*4 ~ 100 KB
    float* bsum = (float*)(ws + (size_t)H * W * 4 + 49 * DIM * 4);  // 2 KB

    int n = in_sizes[1] / 2;  // N points

    hipMemsetAsync(map, 0xFF, (size_t)H * W * sizeof(int), stream);  // -1
    scatter_map_kernel<<<(n + 255) / 256, 256, 0, stream>>>(pos, map, n);
    build_weights_kernel<<<49, DIM, 0, stream>>>(k3, b1, k5, b2, k7, b3, weff, bsum);
    gather_conv_kernel<<<n, 128, 0, stream>>>(x, pos, map, weff, bsum, out);
}

// Round 10
// 227.110 us; speedup vs baseline: 1.0898x; 1.0898x over previous
//
#include <hip/hip_runtime.h>

#define DIM 512
#define H 256
#define W 256

// ---------------------------------------------------------------------------
// Fused prep kernel. Blocks 0..48: fold the three depthwise kernels into one
// effective 7x7 tap table (conv runs on the (W,H)-transposed grid, so offset
// (dh,dw) uses tap w[c, dw+pad, dh+pad]) + bias sum. Blocks 49..: scatter
// point indices onto the cell->index map. NO memset: gather validates entries.
// ---------------------------------------------------------------------------
__global__ __launch_bounds__(512) void prep_kernel(
    const int* __restrict__ pos, int n,
    const float* __restrict__ k3, const float* __restrict__ b1,
    const float* __restrict__ k5, const float* __restrict__ b2,
    const float* __restrict__ k7, const float* __restrict__ b3,
    float* __restrict__ weff, float* __restrict__ bsum,
    int* __restrict__ map) {
    int b = blockIdx.x;
    if (b < 49) {
        int o = b;             // 0..48
        int c = threadIdx.x;   // 0..511
        int dh = o / 7 - 3, dw = o % 7 - 3;
        float v = k7[c * 49 + (dw + 3) * 7 + (dh + 3)];
        if (dh >= -2 && dh <= 2 && dw >= -2 && dw <= 2)
            v += k5[c * 25 + (dw + 2) * 5 + (dh + 2)];
        if (dh >= -1 && dh <= 1 && dw >= -1 && dw <= 1)
            v += k3[c * 9 + (dw + 1) * 3 + (dh + 1)];
        weff[o * DIM + c] = v;
        if (o == 0) bsum[c] = b1[c] + b2[c] + b3[c];
    } else {
        int i = (b - 49) * 512 + threadIdx.x;
        if (i < n) {
            int h = pos[2 * i], w = pos[2 * i + 1];
            map[h * W + w] = i;
        }
    }
}

// ---------------------------------------------------------------------------
// Gather-conv. One block per point, 128 threads x float4 over 512 channels.
// XCD-chunked blockIdx swizzle (T1): consecutive points share an XCD so the
// sorted-order neighbor window (~1.5 MB) stays L2-resident per XCD.
// Probe lanes validate map entries against pos (map is never cleared; poison
// or stale values are rejected by the bounds+coords check).
// Main loop: 4x unrolled, 8 float4 loads in flight before the FMA block.
// out[i,c] = x[i,c] + bsum[c] + sum_valid Weff[o,c] * x[j,c]
// ---------------------------------------------------------------------------
__global__ __launch_bounds__(128) void gather_conv_kernel(
    const float* __restrict__ x, const int* __restrict__ pos,
    const int* __restrict__ map, const float* __restrict__ weff,
    const float* __restrict__ bsum, float* __restrict__ out, int n) {
    int bid = blockIdx.x;
    // bijective only when n % 8 == 0 (n = 32768); fall back to identity else
    int i = ((n & 7) == 0) ? ((bid & 7) * (n >> 3) + (bid >> 3)) : bid;
    int tid = threadIdx.x;

    __shared__ int s_list[49];
    __shared__ int s_cnt;
    if (tid == 0) s_cnt = 0;
    __syncthreads();

    int h = pos[2 * i], w = pos[2 * i + 1];
    if (tid < 49) {
        int dh = tid / 7 - 3, dw = tid % 7 - 3;
        int hh = h + dh, ww = w + dw;
        if (hh >= 0 && hh < H && ww >= 0 && ww < W) {
            int j = map[hh * W + ww];
            if ((unsigned)j < (unsigned)n && pos[2 * j] == hh && pos[2 * j + 1] == ww) {
                int slot = atomicAdd(&s_cnt, 1);
                s_list[slot] = (j << 6) | tid;   // pack: j (15 bits) | offset
            }
        }
    }
    __syncthreads();

    int c = tid * 4;
    float4 acc = *(const float4*)(x + (size_t)i * DIM + c);   // identity (dense add)
    float4 bb  = *(const float4*)(bsum + c);
    acc.x += bb.x; acc.y += bb.y; acc.z += bb.z; acc.w += bb.w;

    int cnt = s_cnt;
    int k = 0;
    for (; k + 4 <= cnt; k += 4) {
        int p0 = s_list[k + 0], p1 = s_list[k + 1];
        int p2 = s_list[k + 2], p3 = s_list[k + 3];
        float4 w0 = *(const float4*)(weff + (p0 & 63) * DIM + c);
        float4 x0 = *(const float4*)(x + (size_t)(p0 >> 6) * DIM + c);
        float4 w1 = *(const float4*)(weff + (p1 & 63) * DIM + c);
        float4 x1 = *(const float4*)(x + (size_t)(p1 >> 6) * DIM + c);
        float4 w2 = *(const float4*)(weff + (p2 & 63) * DIM + c);
        float4 x2 = *(const float4*)(x + (size_t)(p2 >> 6) * DIM + c);
        float4 w3 = *(const float4*)(weff + (p3 & 63) * DIM + c);
        float4 x3 = *(const float4*)(x + (size_t)(p3 >> 6) * DIM + c);
        acc.x = fmaf(w0.x, x0.x, acc.x);
        acc.y = fmaf(w0.y, x0.y, acc.y);
        acc.z = fmaf(w0.z, x0.z, acc.z);
        acc.w = fmaf(w0.w, x0.w, acc.w);
        acc.x = fmaf(w1.x, x1.x, acc.x);
        acc.y = fmaf(w1.y, x1.y, acc.y);
        acc.z = fmaf(w1.z, x1.z, acc.z);
        acc.w = fmaf(w1.w, x1.w, acc.w);
        acc.x = fmaf(w2.x, x2.x, acc.x);
        acc.y = fmaf(w2.y, x2.y, acc.y);
        acc.z = fmaf(w2.z, x2.z, acc.z);
        acc.w = fmaf(w2.w, x2.w, acc.w);
        acc.x = fmaf(w3.x, x3.x, acc.x);
        acc.y = fmaf(w3.y, x3.y, acc.y);
        acc.z = fmaf(w3.z, x3.z, acc.z);
        acc.w = fmaf(w3.w, x3.w, acc.w);
    }
    for (; k < cnt; ++k) {
        int pk = s_list[k];
        float4 wv = *(const float4*)(weff + (pk & 63) * DIM + c);
        float4 xv = *(const float4*)(x + (size_t)(pk >> 6) * DIM + c);
        acc.x = fmaf(wv.x, xv.x, acc.x);
        acc.y = fmaf(wv.y, xv.y, acc.y);
        acc.z = fmaf(wv.z, xv.z, acc.z);
        acc.w = fmaf(wv.w, xv.w, acc.w);
    }
    *(float4*)(out + (size_t)i * DIM + c) = acc;
}

extern "C" void kernel_launch(void* const* d_in, const int* in_sizes, int n_in,
                              void* d_out, int out_size, void* d_ws, size_t ws_size,
                              hipStream_t stream) {
    const float* x   = (const float*)d_in[0];
    const int*   pos = (const int*)d_in[1];
    const float* k3  = (const float*)d_in[2];
    const float* b1  = (const float*)d_in[3];
    const float* k5  = (const float*)d_in[4];
    const float* b2  = (const float*)d_in[5];
    const float* k7  = (const float*)d_in[6];
    const float* b3  = (const float*)d_in[7];
    float* out = (float*)d_out;

    char* ws = (char*)d_ws;
    int*   map  = (int*)ws;                                   // H*W*4   = 256 KB
    float* weff = (float*)(ws + (size_t)H * W * 4);           // 49*512*4 ~ 100 KB
    float* bsum = (float*)(ws + (size_t)H * W * 4 + 49 * DIM * 4);  // 2 KB

    int n = in_sizes[1] / 2;  // N points

    int scatter_blocks = (n + 511) / 512;
    prep_kernel<<<49 + scatter_blocks, 512, 0, stream>>>(
        pos, n, k3, b1, k5, b2, k7, b3, weff, bsum, map);
    gather_conv_kernel<<<n, 128, 0, stream>>>(x, pos, map, weff, bsum, out, n);
}